// Round 1
// baseline (44.722 us; speedup 1.0000x reference)
//
#include <hip/hip_runtime.h>
#include <hip/hip_bf16.h>

// out[b,j] = b2[j] + sum_k w2[j,k] * (h_k - tanh(h_k)),  h_k = W_k·x + b1_k, x = y^3
// W = w1 with rows 0..19 replaced by saved_param.
//
// Folding: tanh(h) = 1 - 2*r, r = 1/(exp2(c*h)+1), c = 2*log2(e).
//   out_j = E_j + A_j0*x0 + A_j1*x1 + sum_{k in active} q_jk * r_k
// where A = w2·W (active rows), q = 2*w2, and E folds b2, w2·b1, -sum(w2),
// plus the constant contribution of "inactive" units (W row == 0 -> h_k = b1_k const).
// Prep kernel (1 wave) computes E/A and a compacted active-unit table in d_ws.

#define NHID 50
#define NVAR 20

__global__ void odefunc_prep(const float* __restrict__ w1,
                             const float* __restrict__ b1,
                             const float* __restrict__ w2,
                             const float* __restrict__ b2,
                             const float* __restrict__ sp,
                             float* __restrict__ ws) {
    int k = threadIdx.x;  // one wave, lanes 0..63; lanes >= NHID idle
    float W0 = 0.f, W1 = 0.f, bk = 0.f, w20 = 0.f, w21 = 0.f;
    float a00 = 0.f, a01 = 0.f, a10 = 0.f, a11 = 0.f, e0 = 0.f, e1 = 0.f;
    bool active = false;
    if (k < NHID) {
        W0 = (k < NVAR) ? sp[2 * k]     : w1[2 * k];
        W1 = (k < NVAR) ? sp[2 * k + 1] : w1[2 * k + 1];
        bk  = b1[k];
        w20 = w2[k];            // w2 is [2,50] row-major
        w21 = w2[NHID + k];
        active = (W0 != 0.f || W1 != 0.f) && (w20 != 0.f || w21 != 0.f);
        if (active) {
            a00 = w20 * W0; a01 = w20 * W1;
            a10 = w21 * W0; a11 = w21 * W1;
            // D_j - sum(w2_jk) = w2_jk * (b1_k - 1)
            e0 = w20 * (bk - 1.f);
            e1 = w21 * (bk - 1.f);
        } else {
            // W row is zero (or w2 col zero): contribution is constant
            float ts = bk - tanhf(bk);
            e0 = w20 * ts;
            e1 = w21 * ts;
        }
    }
    unsigned long long mask = __ballot(active);
    int n = __popcll(mask);
    if (active) {
        int pos = __popcll(mask & ((1ull << k) - 1ull));
        const float c = 2.8853900817779268f;  // 2*log2(e)
        float4* pU = (float4*)(ws + 8);
        pU[pos] = make_float4(c * W0, c * W1, c * bk, 2.f * w20);
        ws[8 + 4 * NHID + pos] = 2.f * w21;
    }
    // wave-reduce the 6 sums
    float vals[6] = {a00, a01, a10, a11, e0, e1};
#pragma unroll
    for (int i = 0; i < 6; i++)
        for (int off = 32; off; off >>= 1)
            vals[i] += __shfl_xor(vals[i], off);
    if (k == 0) {
        ((int*)ws)[0] = n;
        ws[1] = b2[0] + vals[4];  // E0
        ws[2] = b2[1] + vals[5];  // E1
        ws[3] = vals[0];          // A00
        ws[4] = vals[1];          // A01
        ws[5] = vals[2];          // A10
        ws[6] = vals[3];          // A11
    }
}

// 264 floats: [0..7] header, [8..207] float4 units (W'0,W'1,b',q0), [208..257] q1
#define PBYTES 264

__global__ __launch_bounds__(256) void odefunc_main(const float* __restrict__ y,
                                                    const float* __restrict__ wsf,
                                                    float* __restrict__ out,
                                                    int n4) {
    __shared__ __align__(16) float lds[PBYTES];
    for (int i = threadIdx.x; i < PBYTES; i += 256) lds[i] = wsf[i];
    __syncthreads();

    const int n = __float_as_int(lds[0]);
    const float E0 = lds[1], E1 = lds[2];
    const float A00 = lds[3], A01 = lds[4], A10 = lds[5], A11 = lds[6];

    const float4* __restrict__ y4 = (const float4*)y;
    float4* __restrict__ o4 = (float4*)out;

    // each thread: 4 float4s (8 rows), block covers 1024 contiguous float4s
    long long base = (long long)blockIdx.x * 1024 + threadIdx.x;

    float4 vin[4];
#pragma unroll
    for (int j = 0; j < 4; j++) {
        long long idx = base + (long long)j * 256;
        vin[j] = (idx < n4) ? y4[idx] : make_float4(0.f, 0.f, 0.f, 0.f);
    }

    float x0[8], x1[8];
#pragma unroll
    for (int j = 0; j < 4; j++) {
        float a = vin[j].x, b = vin[j].y, cc = vin[j].z, d = vin[j].w;
        x0[2 * j]     = a * a * a;
        x1[2 * j]     = b * b * b;
        x0[2 * j + 1] = cc * cc * cc;
        x1[2 * j + 1] = d * d * d;
    }

    float acc0[8], acc1[8];
#pragma unroll
    for (int r = 0; r < 8; r++) {
        acc0[r] = fmaf(A00, x0[r], fmaf(A01, x1[r], E0));
        acc1[r] = fmaf(A10, x0[r], fmaf(A11, x1[r], E1));
    }

    const float4* pU = (const float4*)(lds + 8);
    const float*  pV = lds + 8 + 4 * NHID;

    for (int k = 0; k < n; k++) {
        float4 p = pU[k];
        float q1 = pV[k];
#pragma unroll
        for (int r = 0; r < 8; r++) {
            float u  = fmaf(p.x, x0[r], fmaf(p.y, x1[r], p.z));
            float t  = __builtin_amdgcn_exp2f(u);
            float rc = __builtin_amdgcn_rcpf(t + 1.f);
            acc0[r] = fmaf(p.w, rc, acc0[r]);
            acc1[r] = fmaf(q1, rc, acc1[r]);
        }
    }

#pragma unroll
    for (int j = 0; j < 4; j++) {
        long long idx = base + (long long)j * 256;
        if (idx < n4) {
            float4 o;
            o.x = acc0[2 * j];
            o.y = acc1[2 * j];
            o.z = acc0[2 * j + 1];
            o.w = acc1[2 * j + 1];
            o4[idx] = o;
        }
    }
}

extern "C" void kernel_launch(void* const* d_in, const int* in_sizes, int n_in,
                              void* d_out, int out_size, void* d_ws, size_t ws_size,
                              hipStream_t stream) {
    // inputs: 0=t(int,1), 1=y(B*2), 2=w1(100), 3=b1(50), 4=w2(100), 5=b2(2), 6=saved_param(40)
    const float* y  = (const float*)d_in[1];
    const float* w1 = (const float*)d_in[2];
    const float* b1 = (const float*)d_in[3];
    const float* w2 = (const float*)d_in[4];
    const float* b2 = (const float*)d_in[5];
    const float* sp = (const float*)d_in[6];
    float* ws  = (float*)d_ws;
    float* out = (float*)d_out;

    odefunc_prep<<<1, 64, 0, stream>>>(w1, b1, w2, b2, sp, ws);

    int n4 = in_sizes[1] / 4;                 // number of float4s in y
    int threads = (n4 + 3) / 4;               // 4 float4s per thread
    int blocks = (threads + 255) / 256;
    odefunc_main<<<blocks, 256, 0, stream>>>(y, ws, out, n4);
}